// Round 7
// baseline (83.816 us; speedup 1.0000x reference)
//
#include <hip/hip_runtime.h>
#include <hip/hip_bf16.h>

#define NN  50000
#define DD  256
#define KNB 16
#define BM  64
#define NSL 8      // column slices (one per XCD)
#define SLW 32     // slice width in columns (64B bf16 rows -> line-pure slices)
#define NKT 8      // 256 / 32

typedef __attribute__((ext_vector_type(8))) short bf16x8;
typedef __attribute__((ext_vector_type(4))) float f32x4;
typedef __attribute__((ext_vector_type(4))) int   i32x4;

static __device__ __forceinline__ float bf2f(unsigned int u16) {
    union { unsigned int i; float f; } c; c.i = u16 << 16; return c.f;
}
static __device__ __forceinline__ float bf2f_hi(unsigned int u) {
    union { unsigned int i; float f; } c; c.i = u & 0xffff0000u; return c.f;
}
static __device__ __forceinline__ short f2bf(float f) {
    union { float f; unsigned int i; } c; c.f = f;
    unsigned int r = c.i + 0x7FFFu + ((c.i >> 16) & 1u);   // RNE
    return (short)(r >> 16);
}
static __device__ __forceinline__ bf16x8 pack8(float4 a, float4 b) {
    union { __hip_bfloat162 h[4]; bf16x8 v; } u;
    u.h[0] = __float22bfloat162_rn(make_float2(a.x, a.y));
    u.h[1] = __float22bfloat162_rn(make_float2(a.z, a.w));
    u.h[2] = __float22bfloat162_rn(make_float2(b.x, b.y));
    u.h[3] = __float22bfloat162_rn(make_float2(b.z, b.w));
    return u.v;
}

#define GLOAD_LDS16(g, l) \
    __builtin_amdgcn_global_load_lds((const __attribute__((address_space(1))) unsigned int*)(g), \
                                     (__attribute__((address_space(3))) unsigned int*)(l), 16, 0, 0)

// ---------------------------------------------------------------------------
// Kernel 0: W (f32, row-major 256x256) -> bf16 fragment-tiled Wbf.
// slot s = ((kt*16 + nb)*4 + kb)*16 + j  holds 8 bf16:
//   Wbf[s*8 + e] = W[nb*16 + j][kt*32 + kb*8 + e]
// ---------------------------------------------------------------------------
__global__ void convert_w(const float* __restrict__ W, unsigned short* __restrict__ Wbf)
{
    int s = blockIdx.x * blockDim.x + threadIdx.x;   // 8192 slots
    if (s >= 8192) return;
    int j  = s & 15;
    int kb = (s >> 4) & 3;
    int nb = (s >> 6) & 15;
    int kt = s >> 10;
    const float4* p = (const float4*)(W + (nb * 16 + j) * DD + kt * 32 + kb * 8);
    *(bf16x8*)&Wbf[(size_t)s * 8] = pack8(p[0], p[1]);
}

// ---------------------------------------------------------------------------
// Kernel 1: x = relu(feats @ W^T + b) -> bf16 in SLICED layout:
//   xs[(col>>5)*NN*32 + row*32 + (col&31)]
// 256 threads = 4 waves; wave wc owns cols [wc*64, wc*64+64). BM=64.
// A (64x256) staged ONCE in prologue (all HBM loads hoisted); W restaged
// per K-step (16 KB, double-buffered) via global_load_lds from L2-resident
// pre-tiled Wbf -> per-step barrier drain is ~300cy L2, not ~900cy HBM.
// LDS = 32 + 32 = 64 KB -> 2 blocks/CU.
// ---------------------------------------------------------------------------
__global__ __launch_bounds__(256, 2) void gemm_relu(
    const float* __restrict__ feats, const unsigned short* __restrict__ Wbf,
    const float* __restrict__ bias, unsigned short* __restrict__ xs)
{
    __shared__ short At[16384];        // 32 KB  [kt8][m4][kq4][i16][e8]
    __shared__ short Wt[2][8192];      // 32 KB  [nb16][kq4][j16][e8] per buf

    const int tid  = threadIdx.x;
    const int lane = tid & 63;
    const int wc   = tid >> 6;
    const int l15  = lane & 15;
    const int lg   = lane >> 4;
    const int blockRow = blockIdx.x * BM;

    auto wstage = [&](int kt, int buf) {
        const char* src = (const char*)Wbf + kt * 16384 + tid * 16;
        char* dst = (char*)&Wt[buf][0] + tid * 16;
        #pragma unroll
        for (int c = 0; c < 4; ++c)
            GLOAD_LDS16(src + c * 4096, dst + c * 4096);
    };

    // ---- stage W(kt=0), then the whole A tile (once) ----
    wstage(0, 0);
    {
        const int r = tid >> 2, q = tid & 3;
        int row = blockRow + r; if (row > NN - 1) row = NN - 1;   // clamp; masked at store
        const float* base = feats + (size_t)row * DD;
        const int m = r >> 4, i15 = r & 15;
        #pragma unroll
        for (int h = 0; h < 4; ++h) {
            float4 v[4];
            #pragma unroll
            for (int j = 0; j < 4; ++j)
                v[j] = *(const float4*)(base + h * 64 + j * 16 + q * 4);
            #pragma unroll
            for (int j = 0; j < 4; ++j) {
                int k0 = h * 64 + j * 16 + q * 4;
                int kt = k0 >> 5, kq = (k0 >> 3) & 3, eo = k0 & 7;
                union { __hip_bfloat162 h2[2]; uint2 u; } p;
                p.h2[0] = __float22bfloat162_rn(make_float2(v[j].x, v[j].y));
                p.h2[1] = __float22bfloat162_rn(make_float2(v[j].z, v[j].w));
                int el = (((kt * 4 + m) * 4 + kq) * 16 + i15) * 8 + eo;
                *(uint2*)&At[el] = p.u;
            }
        }
    }

    float bv[4];
    #pragma unroll
    for (int n = 0; n < 4; ++n) bv[n] = bias[wc * 64 + n * 16 + l15];

    f32x4 acc[4][4];
    #pragma unroll
    for (int m = 0; m < 4; ++m)
        #pragma unroll
        for (int n = 0; n < 4; ++n) acc[m][n] = (f32x4)0.0f;

    __syncthreads();   // A + W(0) ready

    #pragma unroll
    for (int kt = 0; kt < NKT; ++kt) {
        const int cur = kt & 1;
        if (kt + 1 < NKT) wstage(kt + 1, cur ^ 1);   // prefetch next W into other buf

        bf16x8 afr[4], bfr[4];
        #pragma unroll
        for (int m = 0; m < 4; ++m)
            afr[m] = *(const bf16x8*)&At[(((kt * 4 + m) * 4 + lg) * 16 + l15) * 8];
        #pragma unroll
        for (int n = 0; n < 4; ++n)
            bfr[n] = *(const bf16x8*)&Wt[cur][(((wc * 4 + n) * 4 + lg) * 16 + l15) * 8];

        #pragma unroll
        for (int m = 0; m < 4; ++m)
            #pragma unroll
            for (int n = 0; n < 4; ++n)
                acc[m][n] = __builtin_amdgcn_mfma_f32_16x16x32_bf16(
                    afr[m], bfr[n], acc[m][n], 0, 0, 0);

        __syncthreads();   // all waves done with Wt[cur]; next-step writes may land
    }

    // ---- epilogue: bias + relu -> sliced bf16 store ----
    #pragma unroll
    for (int n = 0; n < 4; ++n) {
        const int sl = wc * 2 + (n >> 1);
        const int c  = (n & 1) * 16 + l15;
        unsigned short* xb = xs + (size_t)sl * NN * SLW + c;
        #pragma unroll
        for (int m = 0; m < 4; ++m) {
            int rbase = blockRow + m * 16 + (lg << 2);
            f32x4 a = acc[m][n];
            #pragma unroll
            for (int r = 0; r < 4; ++r) {
                int row = rbase + r;
                if (row < NN) {
                    float vv = fmaxf(a[r] + bv[n], 0.0f);
                    xb[(size_t)row * SLW] = (unsigned short)f2bf(vv);
                }
            }
        }
    }
}

// ---------------------------------------------------------------------------
// Kernel 2: out[i, s*32..s*32+32) = mean_k xs[s][edge[i,k], :].
// Slice s = blockIdx.x & 7 -> pinned to one XCD; its 4MB L2 holds the 3.2MB
// slice. Wave = 16 nodes; lane = node(g) x quad(q), 16B gather loads (4
// lanes/line). Indices loaded per-lane (NT, 4x redundant -> same line) so no
// bpermute chain; NT edge loads keep the slice L2-resident. NT stores.
// ---------------------------------------------------------------------------
__global__ __launch_bounds__(256) void gather_mean(
    const int* __restrict__ edge, const unsigned short* __restrict__ xs,
    float* __restrict__ out)
{
    const int s    = blockIdx.x & 7;
    const int grp  = blockIdx.x >> 3;
    const int lane = threadIdx.x & 63;
    const int w    = threadIdx.x >> 6;
    const int g    = lane >> 2, q = lane & 3;
    const int i    = grp * 64 + w * 16 + g;
    int il = i; if (il > NN - 1) il = NN - 1;

    const i32x4* ep = (const i32x4*)(edge + (size_t)il * KNB);
    i32x4 e0 = __builtin_nontemporal_load(ep);
    i32x4 e1 = __builtin_nontemporal_load(ep + 1);
    i32x4 e2 = __builtin_nontemporal_load(ep + 2);
    i32x4 e3 = __builtin_nontemporal_load(ep + 3);
    int e[16] = { e0[0], e0[1], e0[2], e0[3], e1[0], e1[1], e1[2], e1[3],
                  e2[0], e2[1], e2[2], e2[3], e3[0], e3[1], e3[2], e3[3] };

    const unsigned short* xsl = xs + (size_t)s * NN * SLW;
    const unsigned qo = q * 8;

    float a[8];
    #pragma unroll
    for (int j = 0; j < 8; ++j) a[j] = 0.0f;

    #pragma unroll
    for (int k = 0; k < KNB; ++k) {
        unsigned off = (unsigned)e[k] * SLW + qo;          // 32-bit voffset
        bf16x8 v = *(const bf16x8*)(xsl + off);
        const unsigned int* vu = (const unsigned int*)&v;
        #pragma unroll
        for (int j = 0; j < 4; ++j) {
            a[2 * j]     += bf2f(vu[j] & 0xffffu);
            a[2 * j + 1] += bf2f_hi(vu[j]);
        }
    }

    if (i < NN) {
        f32x4 o0 = { a[0] * 0.0625f, a[1] * 0.0625f, a[2] * 0.0625f, a[3] * 0.0625f };
        f32x4 o1 = { a[4] * 0.0625f, a[5] * 0.0625f, a[6] * 0.0625f, a[7] * 0.0625f };
        float* op = out + (size_t)i * DD + s * SLW + q * 8;
        __builtin_nontemporal_store(o0, (f32x4*)op);
        __builtin_nontemporal_store(o1, (f32x4*)(op + 4));
    }
}

extern "C" void kernel_launch(void* const* d_in, const int* in_sizes, int n_in,
                              void* d_out, int out_size, void* d_ws, size_t ws_size,
                              hipStream_t stream) {
    // inputs: 0:idx 1:feats 2:edge_dict 3:sadj 4:epoch 5:W 6:b
    const float* feats = (const float*)d_in[1];
    const int*   edge  = (const int*)d_in[2];
    const float* W     = (const float*)d_in[5];
    const float* b     = (const float*)d_in[6];
    float* out = (float*)d_out;

    unsigned short* xs  = (unsigned short*)d_ws;                            // 25.6 MB sliced
    unsigned short* Wbf = (unsigned short*)((char*)d_ws + (size_t)NN * DD * 2); // +128 KB

    const int ngrp = (NN + 63) / 64;   // 782
    convert_w<<<dim3(32), dim3(256), 0, stream>>>(W, Wbf);
    gemm_relu<<<dim3(ngrp), dim3(256), 0, stream>>>(feats, Wbf, b, xs);
    gather_mean<<<dim3(ngrp * NSL), dim3(256), 0, stream>>>(edge, xs, out);
}

// Round 8
// 66.530 us; speedup vs baseline: 1.2598x; 1.2598x over previous
//
#include <hip/hip_runtime.h>
#include <hip/hip_bf16.h>

#define NN  50000
#define DD  256
#define KNB 16
#define BM  64
#define NSL 8      // column slices (one per XCD)
#define SLW 32     // slice width in columns (64B bf16 rows -> line-pure slices)
#define NKT 8      // 256 / 32
#define NGRP ((NN + 63) / 64)   // 782 node-groups of 64

typedef __attribute__((ext_vector_type(8))) short bf16x8;
typedef __attribute__((ext_vector_type(4))) float f32x4;
typedef __attribute__((ext_vector_type(4))) int   i32x4;

static __device__ __forceinline__ float bf2f(unsigned int u16) {
    union { unsigned int i; float f; } c; c.i = u16 << 16; return c.f;
}
static __device__ __forceinline__ float bf2f_hi(unsigned int u) {
    union { unsigned int i; float f; } c; c.i = u & 0xffff0000u; return c.f;
}
static __device__ __forceinline__ short f2bf(float f) {
    union { float f; unsigned int i; } c; c.f = f;
    unsigned int r = c.i + 0x7FFFu + ((c.i >> 16) & 1u);   // RNE
    return (short)(r >> 16);
}
static __device__ __forceinline__ bf16x8 pack8(float4 a, float4 b) {
    union { __hip_bfloat162 h[4]; bf16x8 v; } u;
    u.h[0] = __float22bfloat162_rn(make_float2(a.x, a.y));
    u.h[1] = __float22bfloat162_rn(make_float2(a.z, a.w));
    u.h[2] = __float22bfloat162_rn(make_float2(b.x, b.y));
    u.h[3] = __float22bfloat162_rn(make_float2(b.z, b.w));
    return u.v;
}

#define GLOAD_LDS16(g, l) \
    __builtin_amdgcn_global_load_lds((const __attribute__((address_space(1))) unsigned int*)(g), \
                                     (__attribute__((address_space(3))) unsigned int*)(l), 16, 0, 0)

// ---------------------------------------------------------------------------
// Kernel 0: W (f32, row-major 256x256) -> bf16 fragment-tiled Wbf.
// slot s = ((kt*16 + nb)*4 + kb)*16 + j  holds 8 bf16:
//   Wbf[s*8 + e] = W[nb*16 + j][kt*32 + kb*8 + e]
// ---------------------------------------------------------------------------
__global__ void convert_w(const float* __restrict__ W, unsigned short* __restrict__ Wbf)
{
    int s = blockIdx.x * blockDim.x + threadIdx.x;   // 8192 slots
    if (s >= 8192) return;
    int j  = s & 15;
    int kb = (s >> 4) & 3;
    int nb = (s >> 6) & 15;
    int kt = s >> 10;
    const float4* p = (const float4*)(W + (nb * 16 + j) * DD + kt * 32 + kb * 8);
    *(bf16x8*)&Wbf[(size_t)s * 8] = pack8(p[0], p[1]);
}

// ---------------------------------------------------------------------------
// Kernel 1: x = relu(feats @ W^T + b) -> bf16 in SLICED layout:
//   xs[(col>>5)*NN*32 + row*32 + (col&31)]
// 256 threads = 4 waves; wave wc owns cols [wc*64, wc*64+64). BM=64.
// A (64x256) staged ONCE in prologue (all HBM loads hoisted); W restaged
// per K-step (16 KB, double-buffered) via global_load_lds from L2-resident
// pre-tiled Wbf. LDS = 32 + 32 = 64 KB -> 2 blocks/CU.
// ---------------------------------------------------------------------------
__global__ __launch_bounds__(256, 2) void gemm_relu(
    const float* __restrict__ feats, const unsigned short* __restrict__ Wbf,
    const float* __restrict__ bias, unsigned short* __restrict__ xs)
{
    __shared__ short At[16384];        // 32 KB  [kt8][m4][kq4][i16][e8]
    __shared__ short Wt[2][8192];      // 32 KB  [nb16][kq4][j16][e8] per buf

    const int tid  = threadIdx.x;
    const int lane = tid & 63;
    const int wc   = tid >> 6;
    const int l15  = lane & 15;
    const int lg   = lane >> 4;
    const int blockRow = blockIdx.x * BM;

    auto wstage = [&](int kt, int buf) {
        const char* src = (const char*)Wbf + kt * 16384 + tid * 16;
        char* dst = (char*)&Wt[buf][0] + tid * 16;
        #pragma unroll
        for (int c = 0; c < 4; ++c)
            GLOAD_LDS16(src + c * 4096, dst + c * 4096);
    };

    // ---- stage W(kt=0), then the whole A tile (once) ----
    wstage(0, 0);
    {
        const int r = tid >> 2, q = tid & 3;
        int row = blockRow + r; if (row > NN - 1) row = NN - 1;   // clamp; masked at store
        const float* base = feats + (size_t)row * DD;
        const int m = r >> 4, i15 = r & 15;
        #pragma unroll
        for (int h = 0; h < 4; ++h) {
            float4 v[4];
            #pragma unroll
            for (int j = 0; j < 4; ++j)
                v[j] = *(const float4*)(base + h * 64 + j * 16 + q * 4);
            #pragma unroll
            for (int j = 0; j < 4; ++j) {
                int k0 = h * 64 + j * 16 + q * 4;
                int kt = k0 >> 5, kq = (k0 >> 3) & 3, eo = k0 & 7;
                union { __hip_bfloat162 h2[2]; uint2 u; } p;
                p.h2[0] = __float22bfloat162_rn(make_float2(v[j].x, v[j].y));
                p.h2[1] = __float22bfloat162_rn(make_float2(v[j].z, v[j].w));
                int el = (((kt * 4 + m) * 4 + kq) * 16 + i15) * 8 + eo;
                *(uint2*)&At[el] = p.u;
            }
        }
    }

    float bv[4];
    #pragma unroll
    for (int n = 0; n < 4; ++n) bv[n] = bias[wc * 64 + n * 16 + l15];

    f32x4 acc[4][4];
    #pragma unroll
    for (int m = 0; m < 4; ++m)
        #pragma unroll
        for (int n = 0; n < 4; ++n) acc[m][n] = (f32x4)0.0f;

    __syncthreads();   // A + W(0) ready

    #pragma unroll
    for (int kt = 0; kt < NKT; ++kt) {
        const int cur = kt & 1;
        if (kt + 1 < NKT) wstage(kt + 1, cur ^ 1);   // prefetch next W into other buf

        bf16x8 afr[4], bfr[4];
        #pragma unroll
        for (int m = 0; m < 4; ++m)
            afr[m] = *(const bf16x8*)&At[(((kt * 4 + m) * 4 + lg) * 16 + l15) * 8];
        #pragma unroll
        for (int n = 0; n < 4; ++n)
            bfr[n] = *(const bf16x8*)&Wt[cur][(((wc * 4 + n) * 4 + lg) * 16 + l15) * 8];

        #pragma unroll
        for (int m = 0; m < 4; ++m)
            #pragma unroll
            for (int n = 0; n < 4; ++n)
                acc[m][n] = __builtin_amdgcn_mfma_f32_16x16x32_bf16(
                    afr[m], bfr[n], acc[m][n], 0, 0, 0);

        __syncthreads();   // all waves done with Wt[cur]; next-step writes may land
    }

    // ---- epilogue: bias + relu -> sliced bf16 store ----
    #pragma unroll
    for (int n = 0; n < 4; ++n) {
        const int sl = wc * 2 + (n >> 1);
        const int c  = (n & 1) * 16 + l15;
        unsigned short* xb = xs + (size_t)sl * NN * SLW + c;
        #pragma unroll
        for (int m = 0; m < 4; ++m) {
            int rbase = blockRow + m * 16 + (lg << 2);
            f32x4 a = acc[m][n];
            #pragma unroll
            for (int r = 0; r < 4; ++r) {
                int row = rbase + r;
                if (row < NN) {
                    float vv = fmaxf(a[r] + bv[n], 0.0f);
                    xb[(size_t)row * SLW] = (unsigned short)f2bf(vv);
                }
            }
        }
    }
}

// ---------------------------------------------------------------------------
// Kernel 2: out[i, s*32..s*32+32) = mean_k xs[s][edge[i,k], :].
// Persistent grid: 2048 blocks = 256 CU x 8 (all resident). Slice
// s = blockIdx.x & 7 pinned per XCD; its 4MB L2 holds the 3.2MB slice.
// Per iteration a wave handles 16 nodes: coalesced int4 edge load (CACHED --
// NT here was the r7 regression: every edge line became an HBM miss) +
// static __shfl distribution. NT only on the write-once out stores.
// ---------------------------------------------------------------------------
__global__ __launch_bounds__(256) void gather_mean(
    const int* __restrict__ edge, const unsigned short* __restrict__ xs,
    float* __restrict__ out)
{
    const int s    = blockIdx.x & 7;
    const int lane = threadIdx.x & 63;
    const int w    = threadIdx.x >> 6;
    const int g    = lane >> 2, q = lane & 3;
    const unsigned short* xsl = xs + (size_t)s * NN * SLW;
    const unsigned qo = q * 8;

    for (int grp = blockIdx.x >> 3; grp < NGRP; grp += 256) {
        const int iw0 = grp * 64 + w * 16;
        const int i   = iw0 + g;

        // wave's 256 contiguous edge ints: lane -> int4 (fully coalesced, cached)
        int eoff = iw0 * KNB + lane * 4;
        if (eoff > NN * KNB - 4) eoff = NN * KNB - 4;
        i32x4 e4 = *(const i32x4*)(edge + eoff);
        int e[4] = { e4[0], e4[1], e4[2], e4[3] };

        float a[8];
        #pragma unroll
        for (int j = 0; j < 8; ++j) a[j] = 0.0f;

        #pragma unroll
        for (int k = 0; k < KNB; ++k) {
            int src = (lane & 60) | (k >> 2);       // lane holding e[node g][k]
            unsigned n = (unsigned)__shfl(e[k & 3], src, 64);
            bf16x8 v = *(const bf16x8*)(xsl + n * SLW + qo);
            const unsigned int* vu = (const unsigned int*)&v;
            #pragma unroll
            for (int j = 0; j < 4; ++j) {
                a[2 * j]     += bf2f(vu[j] & 0xffffu);
                a[2 * j + 1] += bf2f_hi(vu[j]);
            }
        }

        if (i < NN) {
            f32x4 o0 = { a[0] * 0.0625f, a[1] * 0.0625f, a[2] * 0.0625f, a[3] * 0.0625f };
            f32x4 o1 = { a[4] * 0.0625f, a[5] * 0.0625f, a[6] * 0.0625f, a[7] * 0.0625f };
            float* op = out + (size_t)i * DD + s * SLW + q * 8;
            __builtin_nontemporal_store(o0, (f32x4*)op);
            __builtin_nontemporal_store(o1, (f32x4*)(op + 4));
        }
    }
}

extern "C" void kernel_launch(void* const* d_in, const int* in_sizes, int n_in,
                              void* d_out, int out_size, void* d_ws, size_t ws_size,
                              hipStream_t stream) {
    // inputs: 0:idx 1:feats 2:edge_dict 3:sadj 4:epoch 5:W 6:b
    const float* feats = (const float*)d_in[1];
    const int*   edge  = (const int*)d_in[2];
    const float* W     = (const float*)d_in[5];
    const float* b     = (const float*)d_in[6];
    float* out = (float*)d_out;

    unsigned short* xs  = (unsigned short*)d_ws;                            // 25.6 MB sliced
    unsigned short* Wbf = (unsigned short*)((char*)d_ws + (size_t)NN * DD * 2); // +128 KB

    convert_w<<<dim3(32), dim3(256), 0, stream>>>(W, Wbf);
    gemm_relu<<<dim3(NGRP), dim3(256), 0, stream>>>(feats, Wbf, b, xs);
    gather_mean<<<dim3(2048), dim3(256), 0, stream>>>(edge, xs, out);
}